// Round 9
// baseline (355.151 us; speedup 1.0000x reference)
//
#include <hip/hip_runtime.h>

#define Hn 768
#define Bn 16
#define Sn 512
#define En 32
#define Vn 50265

#define WPB 8           // waves per lm_head block
#define KPW (Hn / WPB)  // 96 k per wave
#define VPB 128         // v per lm_head block
#define CH  6           // k's per ping-pong buffer (96 = 8 * 12)

// ---------------- Layer 1: o1 = g1*inst + (1-g1)*sent, g1 = sigmoid(inst@W1_1 + sent@W1_2)
__global__ __launch_bounds__(256) void gate_layer1(
    const int* __restrict__ batch_arg, const int* __restrict__ event_pos,
    const int* __restrict__ mask_indices, const float* __restrict__ sent_emb,
    const float* __restrict__ emb_table, const float* __restrict__ W1_1,
    const float* __restrict__ W1_2, float* __restrict__ o1_out)
{
    const int b  = blockIdx.x;
    const int j0 = threadIdx.x & 63;
    const int ks = threadIdx.x >> 6;           // wave-uniform
    const int j  = blockIdx.y * 64 + j0;

    const int mask = mask_indices[b];
    int estar = -1;
    #pragma unroll
    for (int e = 0; e < En; ++e)
        if (event_pos[b * En + e] == mask && estar < 0) estar = e;
    const int tok = batch_arg[b * Sn + mask];

    __shared__ __align__(16) float s_inst[Hn];
    __shared__ __align__(16) float s_sent[Hn];
    for (int t = threadIdx.x; t < Hn; t += 256) {
        s_inst[t] = emb_table[(size_t)tok * Hn + t];
        s_sent[t] = (estar >= 0) ? sent_emb[((size_t)b * En + estar) * Hn + t] : 0.f;
    }
    __syncthreads();

    float a0 = 0.f, a1 = 0.f, c0 = 0.f, c1 = 0.f;
    const float* __restrict__ w1 = W1_1 + (size_t)ks * 192 * Hn + j;
    const float* __restrict__ w2 = W1_2 + (size_t)ks * 192 * Hn + j;
    const float4* __restrict__ si = (const float4*)(s_inst + ks * 192);
    const float4* __restrict__ ss = (const float4*)(s_sent + ks * 192);
    #pragma unroll 4
    for (int k4 = 0; k4 < 48; ++k4) {
        const float4 iv = si[k4];
        const float4 sv = ss[k4];
        const float* __restrict__ wa = w1 + (size_t)k4 * 4 * Hn;
        const float* __restrict__ wb = w2 + (size_t)k4 * 4 * Hn;
        a0 = fmaf(iv.x, wa[0],      a0);
        a1 = fmaf(iv.y, wa[Hn],     a1);
        a0 = fmaf(iv.z, wa[2 * Hn], a0);
        a1 = fmaf(iv.w, wa[3 * Hn], a1);
        c0 = fmaf(sv.x, wb[0],      c0);
        c1 = fmaf(sv.y, wb[Hn],     c1);
        c0 = fmaf(sv.z, wb[2 * Hn], c0);
        c1 = fmaf(sv.w, wb[3 * Hn], c1);
    }

    __shared__ float r_a[4][64];
    __shared__ float r_c[4][64];
    r_a[ks][j0] = a0 + a1; r_c[ks][j0] = c0 + c1;
    __syncthreads();
    if (ks == 0) {
        const float A = r_a[0][j0] + r_a[1][j0] + r_a[2][j0] + r_a[3][j0];
        const float C = r_c[0][j0] + r_c[1][j0] + r_c[2][j0] + r_c[3][j0];
        const float g = 1.f / (1.f + expf(-(A + C)));
        o1_out[b * Hn + j] = g * s_inst[j] + (1.f - g) * s_sent[j];
    }
}

// ---------------- Layer 2: o2 = g2*o1 + (1-g2)*typ, written TRANSPOSED as me_t[k][b]
__global__ __launch_bounds__(256) void gate_layer2(
    const int* __restrict__ batch_arg, const int* __restrict__ event_pos,
    const int* __restrict__ mask_indices, const float* __restrict__ type_emb,
    const float* __restrict__ emb_table, const float* __restrict__ W2_1,
    const float* __restrict__ W2_2, const float* __restrict__ o1_in,
    float* __restrict__ me_t)
{
    const int b  = blockIdx.x;
    const int j0 = threadIdx.x & 63;
    const int ks = threadIdx.x >> 6;
    const int j  = blockIdx.y * 64 + j0;

    const int mask = mask_indices[b];
    int estar = -1;
    #pragma unroll
    for (int e = 0; e < En; ++e)
        if (event_pos[b * En + e] == mask && estar < 0) estar = e;
    const int tok = batch_arg[b * Sn + mask];

    __shared__ __align__(16) float s_o1[Hn];
    __shared__ __align__(16) float s_typ[Hn];
    for (int t = threadIdx.x; t < Hn; t += 256) {
        s_o1[t]  = o1_in[b * Hn + t];
        s_typ[t] = type_emb[((size_t)b * Sn + mask) * Hn + t];
    }
    __syncthreads();

    float a0 = 0.f, a1 = 0.f, c0 = 0.f, c1 = 0.f;
    const float* __restrict__ w1 = W2_1 + (size_t)ks * 192 * Hn + j;
    const float* __restrict__ w2 = W2_2 + (size_t)ks * 192 * Hn + j;
    const float4* __restrict__ so = (const float4*)(s_o1  + ks * 192);
    const float4* __restrict__ st = (const float4*)(s_typ + ks * 192);
    #pragma unroll 4
    for (int k4 = 0; k4 < 48; ++k4) {
        const float4 ov = so[k4];
        const float4 tv = st[k4];
        const float* __restrict__ wa = w1 + (size_t)k4 * 4 * Hn;
        const float* __restrict__ wb = w2 + (size_t)k4 * 4 * Hn;
        a0 = fmaf(ov.x, wa[0],      a0);
        a1 = fmaf(ov.y, wa[Hn],     a1);
        a0 = fmaf(ov.z, wa[2 * Hn], a0);
        a1 = fmaf(ov.w, wa[3 * Hn], a1);
        c0 = fmaf(tv.x, wb[0],      c0);
        c1 = fmaf(tv.y, wb[Hn],     c1);
        c0 = fmaf(tv.z, wb[2 * Hn], c0);
        c1 = fmaf(tv.w, wb[3 * Hn], c1);
    }

    __shared__ float r_a[4][64];
    __shared__ float r_c[4][64];
    r_a[ks][j0] = a0 + a1; r_c[ks][j0] = c0 + c1;
    __syncthreads();
    if (ks == 0) {
        const float A = r_a[0][j0] + r_a[1][j0] + r_a[2][j0] + r_a[3][j0];
        const float C = r_c[0][j0] + r_c[1][j0] + r_c[2][j0] + r_c[3][j0];
        const float g = 1.f / (1.f + expf(-(A + C)));
        float o2 = g * s_o1[j] + (1.f - g) * s_typ[j];
        if (estar < 0) o2 = emb_table[(size_t)tok * Hn + j];  // mask row never updated
        me_t[j * Bn + b] = o2;
    }
}

// ---------------- LM head: out[b][v] = sum_k me_t[k][b]*lm_W[k][v] + lm_b[v]
// 393 blocks x 512 threads. Thread = 4 v (float4 W) x 8 b. me_t in LDS
// (lgkmcnt stream). lm_W: TRUE ping-pong (named bufA/bufB, NO copy) so the
// compiler emits counted vmcnt waits -- one buffer's 6 loads always stay in
// flight while the other is consumed. smem reused for cross-wave reduction.
__global__ __launch_bounds__(512, 4) void lm_head(
    const float* __restrict__ me_t, const float* __restrict__ lm_W,
    const float* __restrict__ lm_b, float* __restrict__ out)
{
    __shared__ __align__(16) float smem[WPB * Bn * VPB];   // 64 KB (me stage, then red)

    const int tid  = threadIdx.x;
    const int lane = tid & 63;
    const int w    = tid >> 6;                    // 0..7
    const int bh   = lane & 1;                    // b-half: 0 -> b0-7, 1 -> b8-15
    const int vq   = lane >> 1;                   // 0..31
    const int v0   = blockIdx.x * VPB + vq * 4;   // four consecutive v's

    // ---- stage me_t (Hn*Bn = 12288 floats = 48 KB) into LDS, coalesced
    {
        const float4* __restrict__ src = (const float4*)me_t;
        float4* __restrict__ dst = (float4*)smem;
        #pragma unroll
        for (int i = 0; i < 6; ++i)
            dst[i * 512 + tid] = src[i * 512 + tid];
    }
    __syncthreads();

    const int kb = w * KPW;
    float4 acc[8];
    #pragma unroll
    for (int i = 0; i < 8; ++i) acc[i] = make_float4(0.f, 0.f, 0.f, 0.f);

    const float* __restrict__ mb = smem + kb * Bn + bh * 8;   // me[k][bh*8 + ...]

#define FMA32(wv, m0, m1)                                                     \
    acc[0].x = fmaf(m0.x, wv.x, acc[0].x); acc[0].y = fmaf(m0.x, wv.y, acc[0].y); \
    acc[0].z = fmaf(m0.x, wv.z, acc[0].z); acc[0].w = fmaf(m0.x, wv.w, acc[0].w); \
    acc[1].x = fmaf(m0.y, wv.x, acc[1].x); acc[1].y = fmaf(m0.y, wv.y, acc[1].y); \
    acc[1].z = fmaf(m0.y, wv.z, acc[1].z); acc[1].w = fmaf(m0.y, wv.w, acc[1].w); \
    acc[2].x = fmaf(m0.z, wv.x, acc[2].x); acc[2].y = fmaf(m0.z, wv.y, acc[2].y); \
    acc[2].z = fmaf(m0.z, wv.z, acc[2].z); acc[2].w = fmaf(m0.z, wv.w, acc[2].w); \
    acc[3].x = fmaf(m0.w, wv.x, acc[3].x); acc[3].y = fmaf(m0.w, wv.y, acc[3].y); \
    acc[3].z = fmaf(m0.w, wv.z, acc[3].z); acc[3].w = fmaf(m0.w, wv.w, acc[3].w); \
    acc[4].x = fmaf(m1.x, wv.x, acc[4].x); acc[4].y = fmaf(m1.x, wv.y, acc[4].y); \
    acc[4].z = fmaf(m1.x, wv.z, acc[4].z); acc[4].w = fmaf(m1.x, wv.w, acc[4].w); \
    acc[5].x = fmaf(m1.y, wv.x, acc[5].x); acc[5].y = fmaf(m1.y, wv.y, acc[5].y); \
    acc[5].z = fmaf(m1.y, wv.z, acc[5].z); acc[5].w = fmaf(m1.y, wv.w, acc[5].w); \
    acc[6].x = fmaf(m1.z, wv.x, acc[6].x); acc[6].y = fmaf(m1.z, wv.y, acc[6].y); \
    acc[6].z = fmaf(m1.z, wv.z, acc[6].z); acc[6].w = fmaf(m1.z, wv.w, acc[6].w); \
    acc[7].x = fmaf(m1.w, wv.x, acc[7].x); acc[7].y = fmaf(m1.w, wv.y, acc[7].y); \
    acc[7].z = fmaf(m1.w, wv.z, acc[7].z); acc[7].w = fmaf(m1.w, wv.w, acc[7].w);

    if (__all(v0 + 3 < Vn)) {
        // ---- fast path: ping-pong register pipeline, single vmcnt stream
        const float* __restrict__ wp = lm_W + (size_t)kb * Vn + v0;
        float4 bufA[CH], bufB[CH];
        #pragma unroll
        for (int u = 0; u < CH; ++u)
            bufA[u] = *(const float4*)(wp + (size_t)u * Vn);
        #pragma unroll
        for (int u = 0; u < CH; ++u)
            bufB[u] = *(const float4*)(wp + (size_t)(CH + u) * Vn);

        for (int k0 = 0; k0 < KPW; k0 += 2 * CH) {
            // consume A (vmcnt retires only A's loads; B's stay in flight)
            #pragma unroll
            for (int u = 0; u < CH; ++u) {
                const float4 wv = bufA[u];
                const float4 m0 = *(const float4*)(mb + (k0 + u) * Bn);
                const float4 m1 = *(const float4*)(mb + (k0 + u) * Bn + 4);
                FMA32(wv, m0, m1)
            }
            if (k0 + 2 * CH < KPW) {               // refill A two chunks ahead
                #pragma unroll
                for (int u = 0; u < CH; ++u)
                    bufA[u] = *(const float4*)(wp + (size_t)(k0 + 2 * CH + u) * Vn);
            }
            // consume B
            #pragma unroll
            for (int u = 0; u < CH; ++u) {
                const float4 wv = bufB[u];
                const float4 m0 = *(const float4*)(mb + (k0 + CH + u) * Bn);
                const float4 m1 = *(const float4*)(mb + (k0 + CH + u) * Bn + 4);
                FMA32(wv, m0, m1)
            }
            if (k0 + 3 * CH < KPW) {               // refill B two chunks ahead
                #pragma unroll
                for (int u = 0; u < CH; ++u)
                    bufB[u] = *(const float4*)(wp + (size_t)(k0 + 3 * CH + u) * Vn);
            }
        }
    } else {
        // ---- tail path (wave-uniform; last block only): clamped scalar loads.
        const float* __restrict__ wq = lm_W + (size_t)kb * Vn;
        const int vx0 = (v0     < Vn) ? v0     : (Vn - 1);
        const int vx1 = (v0 + 1 < Vn) ? v0 + 1 : (Vn - 1);
        const int vx2 = (v0 + 2 < Vn) ? v0 + 2 : (Vn - 1);
        const int vx3 = (v0 + 3 < Vn) ? v0 + 3 : (Vn - 1);
        for (int k = 0; k < KPW; ++k) {
            float4 wv;
            wv.x = wq[(size_t)k * Vn + vx0];
            wv.y = wq[(size_t)k * Vn + vx1];
            wv.z = wq[(size_t)k * Vn + vx2];
            wv.w = wq[(size_t)k * Vn + vx3];
            const float4 m0 = *(const float4*)(mb + k * Bn);
            const float4 m1 = *(const float4*)(mb + k * Bn + 4);
            FMA32(wv, m0, m1)
        }
    }
#undef FMA32

    __syncthreads();                              // all me reads done; reuse smem
    #pragma unroll
    for (int i = 0; i < 8; ++i)
        *(float4*)&smem[((w * Bn) + bh * 8 + i) * VPB + vq * 4] = acc[i];
    __syncthreads();

    #pragma unroll
    for (int p0 = 0; p0 < 4; ++p0) {
        const int p  = p0 * 512 + tid;            // 0..2047 = 16 b x 128 v
        const int b  = p >> 7;
        const int l  = p & 127;
        const int vv = blockIdx.x * VPB + l;
        if (vv < Vn) {
            float s = 0.f;
            #pragma unroll
            for (int ww = 0; ww < WPB; ++ww) s += smem[(ww * Bn + b) * VPB + l];
            out[(size_t)b * Vn + vv] = s + lm_b[vv];
        }
    }
}

extern "C" void kernel_launch(void* const* d_in, const int* in_sizes, int n_in,
                              void* d_out, int out_size, void* d_ws, size_t ws_size,
                              hipStream_t stream) {
    const int*   batch_arg    = (const int*)  d_in[0];
    const int*   event_pos    = (const int*)  d_in[1];
    const int*   mask_indices = (const int*)  d_in[2];
    const float* sent_emb     = (const float*)d_in[3];
    const float* type_emb     = (const float*)d_in[4];
    const float* emb_table    = (const float*)d_in[5];
    const float* W1_1         = (const float*)d_in[6];
    const float* W1_2         = (const float*)d_in[7];
    const float* W2_1         = (const float*)d_in[8];
    const float* W2_2         = (const float*)d_in[9];
    const float* lm_W         = (const float*)d_in[10];
    const float* lm_b         = (const float*)d_in[11];
    float* out = (float*)d_out;

    float* o1_ws = (float*)d_ws;                 // Bn*Hn floats
    float* me_t  = o1_ws + (size_t)Bn * Hn;      // Hn*Bn floats (16B aligned)

    dim3 g12(Bn, Hn / 64);
    gate_layer1<<<g12, 256, 0, stream>>>(batch_arg, event_pos, mask_indices,
                                         sent_emb, emb_table, W1_1, W1_2, o1_ws);
    gate_layer2<<<g12, 256, 0, stream>>>(batch_arg, event_pos, mask_indices,
                                         type_emb, emb_table, W2_1, W2_2, o1_ws, me_t);

    lm_head<<<(Vn + VPB - 1) / VPB, 512, 0, stream>>>(me_t, lm_W, lm_b, out);
}

// Round 10
// 67.163 us; speedup vs baseline: 5.2879x; 5.2879x over previous
//
#include <hip/hip_runtime.h>

#define Hn 768
#define Bn 16
#define Sn 512
#define En 32
#define Vn 50265

#define WPB 8           // waves per lm_head block
#define KPW (Hn / WPB)  // 96 k per wave
#define VPB 128         // v per lm_head block
#define CH  6           // k's per ping-pong buffer (96 = 8 * 12)

// ---------------- Layer 1: o1 = g1*inst + (1-g1)*sent, g1 = sigmoid(inst@W1_1 + sent@W1_2)
__global__ __launch_bounds__(256) void gate_layer1(
    const int* __restrict__ batch_arg, const int* __restrict__ event_pos,
    const int* __restrict__ mask_indices, const float* __restrict__ sent_emb,
    const float* __restrict__ emb_table, const float* __restrict__ W1_1,
    const float* __restrict__ W1_2, float* __restrict__ o1_out)
{
    const int b  = blockIdx.x;
    const int j0 = threadIdx.x & 63;
    const int ks = threadIdx.x >> 6;           // wave-uniform
    const int j  = blockIdx.y * 64 + j0;

    const int mask = mask_indices[b];
    int estar = -1;
    #pragma unroll
    for (int e = 0; e < En; ++e)
        if (event_pos[b * En + e] == mask && estar < 0) estar = e;
    const int tok = batch_arg[b * Sn + mask];

    __shared__ __align__(16) float s_inst[Hn];
    __shared__ __align__(16) float s_sent[Hn];
    for (int t = threadIdx.x; t < Hn; t += 256) {
        s_inst[t] = emb_table[(size_t)tok * Hn + t];
        s_sent[t] = (estar >= 0) ? sent_emb[((size_t)b * En + estar) * Hn + t] : 0.f;
    }
    __syncthreads();

    float a0 = 0.f, a1 = 0.f, c0 = 0.f, c1 = 0.f;
    const float* __restrict__ w1 = W1_1 + (size_t)ks * 192 * Hn + j;
    const float* __restrict__ w2 = W1_2 + (size_t)ks * 192 * Hn + j;
    const float4* __restrict__ si = (const float4*)(s_inst + ks * 192);
    const float4* __restrict__ ss = (const float4*)(s_sent + ks * 192);
    #pragma unroll 4
    for (int k4 = 0; k4 < 48; ++k4) {
        const float4 iv = si[k4];
        const float4 sv = ss[k4];
        const float* __restrict__ wa = w1 + (size_t)k4 * 4 * Hn;
        const float* __restrict__ wb = w2 + (size_t)k4 * 4 * Hn;
        a0 = fmaf(iv.x, wa[0],      a0);
        a1 = fmaf(iv.y, wa[Hn],     a1);
        a0 = fmaf(iv.z, wa[2 * Hn], a0);
        a1 = fmaf(iv.w, wa[3 * Hn], a1);
        c0 = fmaf(sv.x, wb[0],      c0);
        c1 = fmaf(sv.y, wb[Hn],     c1);
        c0 = fmaf(sv.z, wb[2 * Hn], c0);
        c1 = fmaf(sv.w, wb[3 * Hn], c1);
    }

    __shared__ float r_a[4][64];
    __shared__ float r_c[4][64];
    r_a[ks][j0] = a0 + a1; r_c[ks][j0] = c0 + c1;
    __syncthreads();
    if (ks == 0) {
        const float A = r_a[0][j0] + r_a[1][j0] + r_a[2][j0] + r_a[3][j0];
        const float C = r_c[0][j0] + r_c[1][j0] + r_c[2][j0] + r_c[3][j0];
        const float g = 1.f / (1.f + expf(-(A + C)));
        o1_out[b * Hn + j] = g * s_inst[j] + (1.f - g) * s_sent[j];
    }
}

// ---------------- Layer 2: o2 = g2*o1 + (1-g2)*typ, written TRANSPOSED as me_t[k][b]
__global__ __launch_bounds__(256) void gate_layer2(
    const int* __restrict__ batch_arg, const int* __restrict__ event_pos,
    const int* __restrict__ mask_indices, const float* __restrict__ type_emb,
    const float* __restrict__ emb_table, const float* __restrict__ W2_1,
    const float* __restrict__ W2_2, const float* __restrict__ o1_in,
    float* __restrict__ me_t)
{
    const int b  = blockIdx.x;
    const int j0 = threadIdx.x & 63;
    const int ks = threadIdx.x >> 6;
    const int j  = blockIdx.y * 64 + j0;

    const int mask = mask_indices[b];
    int estar = -1;
    #pragma unroll
    for (int e = 0; e < En; ++e)
        if (event_pos[b * En + e] == mask && estar < 0) estar = e;
    const int tok = batch_arg[b * Sn + mask];

    __shared__ __align__(16) float s_o1[Hn];
    __shared__ __align__(16) float s_typ[Hn];
    for (int t = threadIdx.x; t < Hn; t += 256) {
        s_o1[t]  = o1_in[b * Hn + t];
        s_typ[t] = type_emb[((size_t)b * Sn + mask) * Hn + t];
    }
    __syncthreads();

    float a0 = 0.f, a1 = 0.f, c0 = 0.f, c1 = 0.f;
    const float* __restrict__ w1 = W2_1 + (size_t)ks * 192 * Hn + j;
    const float* __restrict__ w2 = W2_2 + (size_t)ks * 192 * Hn + j;
    const float4* __restrict__ so = (const float4*)(s_o1  + ks * 192);
    const float4* __restrict__ st = (const float4*)(s_typ + ks * 192);
    #pragma unroll 4
    for (int k4 = 0; k4 < 48; ++k4) {
        const float4 ov = so[k4];
        const float4 tv = st[k4];
        const float* __restrict__ wa = w1 + (size_t)k4 * 4 * Hn;
        const float* __restrict__ wb = w2 + (size_t)k4 * 4 * Hn;
        a0 = fmaf(ov.x, wa[0],      a0);
        a1 = fmaf(ov.y, wa[Hn],     a1);
        a0 = fmaf(ov.z, wa[2 * Hn], a0);
        a1 = fmaf(ov.w, wa[3 * Hn], a1);
        c0 = fmaf(tv.x, wb[0],      c0);
        c1 = fmaf(tv.y, wb[Hn],     c1);
        c0 = fmaf(tv.z, wb[2 * Hn], c0);
        c1 = fmaf(tv.w, wb[3 * Hn], c1);
    }

    __shared__ float r_a[4][64];
    __shared__ float r_c[4][64];
    r_a[ks][j0] = a0 + a1; r_c[ks][j0] = c0 + c1;
    __syncthreads();
    if (ks == 0) {
        const float A = r_a[0][j0] + r_a[1][j0] + r_a[2][j0] + r_a[3][j0];
        const float C = r_c[0][j0] + r_c[1][j0] + r_c[2][j0] + r_c[3][j0];
        const float g = 1.f / (1.f + expf(-(A + C)));
        float o2 = g * s_o1[j] + (1.f - g) * s_typ[j];
        if (estar < 0) o2 = emb_table[(size_t)tok * Hn + j];  // mask row never updated
        me_t[j * Bn + b] = o2;
    }
}

// ---------------- LM head: out[b][v] = sum_k me_t[k][b]*lm_W[k][v] + lm_b[v]
// 393 blocks x 512 threads. Thread = 4 v (float4 W) x 8 b. me_t in LDS
// (lgkmcnt stream). lm_W: TRUE ping-pong (named bufA/bufB, NO copy) so the
// compiler emits counted vmcnt waits -- one buffer's 6 loads always stay in
// flight while the other is consumed. smem reused for cross-wave reduction.
// __launch_bounds__(512,2): VGPR cap 256 (~110 needed). (512,4) capped at 64
// and spilled 1.2 GB/dispatch to scratch -- R9 regression.
__global__ __launch_bounds__(512, 2) void lm_head(
    const float* __restrict__ me_t, const float* __restrict__ lm_W,
    const float* __restrict__ lm_b, float* __restrict__ out)
{
    __shared__ __align__(16) float smem[WPB * Bn * VPB];   // 64 KB (me stage, then red)

    const int tid  = threadIdx.x;
    const int lane = tid & 63;
    const int w    = tid >> 6;                    // 0..7
    const int bh   = lane & 1;                    // b-half: 0 -> b0-7, 1 -> b8-15
    const int vq   = lane >> 1;                   // 0..31
    const int v0   = blockIdx.x * VPB + vq * 4;   // four consecutive v's

    // ---- stage me_t (Hn*Bn = 12288 floats = 48 KB) into LDS, coalesced
    {
        const float4* __restrict__ src = (const float4*)me_t;
        float4* __restrict__ dst = (float4*)smem;
        #pragma unroll
        for (int i = 0; i < 6; ++i)
            dst[i * 512 + tid] = src[i * 512 + tid];
    }
    __syncthreads();

    const int kb = w * KPW;
    float4 acc[8];
    #pragma unroll
    for (int i = 0; i < 8; ++i) acc[i] = make_float4(0.f, 0.f, 0.f, 0.f);

    const float* __restrict__ mb = smem + kb * Bn + bh * 8;   // me[k][bh*8 + ...]

#define FMA32(wv, m0, m1)                                                     \
    acc[0].x = fmaf(m0.x, wv.x, acc[0].x); acc[0].y = fmaf(m0.x, wv.y, acc[0].y); \
    acc[0].z = fmaf(m0.x, wv.z, acc[0].z); acc[0].w = fmaf(m0.x, wv.w, acc[0].w); \
    acc[1].x = fmaf(m0.y, wv.x, acc[1].x); acc[1].y = fmaf(m0.y, wv.y, acc[1].y); \
    acc[1].z = fmaf(m0.y, wv.z, acc[1].z); acc[1].w = fmaf(m0.y, wv.w, acc[1].w); \
    acc[2].x = fmaf(m0.z, wv.x, acc[2].x); acc[2].y = fmaf(m0.z, wv.y, acc[2].y); \
    acc[2].z = fmaf(m0.z, wv.z, acc[2].z); acc[2].w = fmaf(m0.z, wv.w, acc[2].w); \
    acc[3].x = fmaf(m0.w, wv.x, acc[3].x); acc[3].y = fmaf(m0.w, wv.y, acc[3].y); \
    acc[3].z = fmaf(m0.w, wv.z, acc[3].z); acc[3].w = fmaf(m0.w, wv.w, acc[3].w); \
    acc[4].x = fmaf(m1.x, wv.x, acc[4].x); acc[4].y = fmaf(m1.x, wv.y, acc[4].y); \
    acc[4].z = fmaf(m1.x, wv.z, acc[4].z); acc[4].w = fmaf(m1.x, wv.w, acc[4].w); \
    acc[5].x = fmaf(m1.y, wv.x, acc[5].x); acc[5].y = fmaf(m1.y, wv.y, acc[5].y); \
    acc[5].z = fmaf(m1.y, wv.z, acc[5].z); acc[5].w = fmaf(m1.y, wv.w, acc[5].w); \
    acc[6].x = fmaf(m1.z, wv.x, acc[6].x); acc[6].y = fmaf(m1.z, wv.y, acc[6].y); \
    acc[6].z = fmaf(m1.z, wv.z, acc[6].z); acc[6].w = fmaf(m1.z, wv.w, acc[6].w); \
    acc[7].x = fmaf(m1.w, wv.x, acc[7].x); acc[7].y = fmaf(m1.w, wv.y, acc[7].y); \
    acc[7].z = fmaf(m1.w, wv.z, acc[7].z); acc[7].w = fmaf(m1.w, wv.w, acc[7].w);

    if (__all(v0 + 3 < Vn)) {
        // ---- fast path: ping-pong register pipeline, single vmcnt stream
        const float* __restrict__ wp = lm_W + (size_t)kb * Vn + v0;
        float4 bufA[CH], bufB[CH];
        #pragma unroll
        for (int u = 0; u < CH; ++u)
            bufA[u] = *(const float4*)(wp + (size_t)u * Vn);
        #pragma unroll
        for (int u = 0; u < CH; ++u)
            bufB[u] = *(const float4*)(wp + (size_t)(CH + u) * Vn);

        for (int k0 = 0; k0 < KPW; k0 += 2 * CH) {
            // consume A (vmcnt retires only A's loads; B's stay in flight)
            #pragma unroll
            for (int u = 0; u < CH; ++u) {
                const float4 wv = bufA[u];
                const float4 m0 = *(const float4*)(mb + (k0 + u) * Bn);
                const float4 m1 = *(const float4*)(mb + (k0 + u) * Bn + 4);
                FMA32(wv, m0, m1)
            }
            if (k0 + 2 * CH < KPW) {               // refill A two chunks ahead
                #pragma unroll
                for (int u = 0; u < CH; ++u)
                    bufA[u] = *(const float4*)(wp + (size_t)(k0 + 2 * CH + u) * Vn);
            }
            // consume B
            #pragma unroll
            for (int u = 0; u < CH; ++u) {
                const float4 wv = bufB[u];
                const float4 m0 = *(const float4*)(mb + (k0 + CH + u) * Bn);
                const float4 m1 = *(const float4*)(mb + (k0 + CH + u) * Bn + 4);
                FMA32(wv, m0, m1)
            }
            if (k0 + 3 * CH < KPW) {               // refill B two chunks ahead
                #pragma unroll
                for (int u = 0; u < CH; ++u)
                    bufB[u] = *(const float4*)(wp + (size_t)(k0 + 3 * CH + u) * Vn);
            }
        }
    } else {
        // ---- tail path (wave-uniform; last block only): clamped scalar loads.
        const float* __restrict__ wq = lm_W + (size_t)kb * Vn;
        const int vx0 = (v0     < Vn) ? v0     : (Vn - 1);
        const int vx1 = (v0 + 1 < Vn) ? v0 + 1 : (Vn - 1);
        const int vx2 = (v0 + 2 < Vn) ? v0 + 2 : (Vn - 1);
        const int vx3 = (v0 + 3 < Vn) ? v0 + 3 : (Vn - 1);
        for (int k = 0; k < KPW; ++k) {
            float4 wv;
            wv.x = wq[(size_t)k * Vn + vx0];
            wv.y = wq[(size_t)k * Vn + vx1];
            wv.z = wq[(size_t)k * Vn + vx2];
            wv.w = wq[(size_t)k * Vn + vx3];
            const float4 m0 = *(const float4*)(mb + k * Bn);
            const float4 m1 = *(const float4*)(mb + k * Bn + 4);
            FMA32(wv, m0, m1)
        }
    }
#undef FMA32

    __syncthreads();                              // all me reads done; reuse smem
    #pragma unroll
    for (int i = 0; i < 8; ++i)
        *(float4*)&smem[((w * Bn) + bh * 8 + i) * VPB + vq * 4] = acc[i];
    __syncthreads();

    #pragma unroll
    for (int p0 = 0; p0 < 4; ++p0) {
        const int p  = p0 * 512 + tid;            // 0..2047 = 16 b x 128 v
        const int b  = p >> 7;
        const int l  = p & 127;
        const int vv = blockIdx.x * VPB + l;
        if (vv < Vn) {
            float s = 0.f;
            #pragma unroll
            for (int ww = 0; ww < WPB; ++ww) s += smem[(ww * Bn + b) * VPB + l];
            out[(size_t)b * Vn + vv] = s + lm_b[vv];
        }
    }
}

extern "C" void kernel_launch(void* const* d_in, const int* in_sizes, int n_in,
                              void* d_out, int out_size, void* d_ws, size_t ws_size,
                              hipStream_t stream) {
    const int*   batch_arg    = (const int*)  d_in[0];
    const int*   event_pos    = (const int*)  d_in[1];
    const int*   mask_indices = (const int*)  d_in[2];
    const float* sent_emb     = (const float*)d_in[3];
    const float* type_emb     = (const float*)d_in[4];
    const float* emb_table    = (const float*)d_in[5];
    const float* W1_1         = (const float*)d_in[6];
    const float* W1_2         = (const float*)d_in[7];
    const float* W2_1         = (const float*)d_in[8];
    const float* W2_2         = (const float*)d_in[9];
    const float* lm_W         = (const float*)d_in[10];
    const float* lm_b         = (const float*)d_in[11];
    float* out = (float*)d_out;

    float* o1_ws = (float*)d_ws;                 // Bn*Hn floats
    float* me_t  = o1_ws + (size_t)Bn * Hn;      // Hn*Bn floats (16B aligned)

    dim3 g12(Bn, Hn / 64);
    gate_layer1<<<g12, 256, 0, stream>>>(batch_arg, event_pos, mask_indices,
                                         sent_emb, emb_table, W1_1, W1_2, o1_ws);
    gate_layer2<<<g12, 256, 0, stream>>>(batch_arg, event_pos, mask_indices,
                                         type_emb, emb_table, W2_1, W2_2, o1_ws, me_t);

    lm_head<<<(Vn + VPB - 1) / VPB, 512, 0, stream>>>(me_t, lm_W, lm_b, out);
}